// Round 1
// baseline (6705.486 us; speedup 1.0000x reference)
//
#include <hip/hip_runtime.h>

#define NN 50000
#define EE 800000
#define GG 512

#define BM 64
#define BN 64
#define BK 16

// ---------------- init kernels ----------------

__global__ void count_deg(const int* __restrict__ dst, float* __restrict__ deg) {
    int e = blockIdx.x * blockDim.x + threadIdx.x;
    if (e < EE) atomicAdd(&deg[dst[e]], 1.0f);
}

__global__ void count_g(const int* __restrict__ gid, float* __restrict__ gcnt) {
    int n = blockIdx.x * blockDim.x + threadIdx.x;
    if (n < NN) atomicAdd(&gcnt[gid[n]], 1.0f);
}

__global__ void finalize_init(float* __restrict__ deg, float* __restrict__ gcnt,
                              float* __restrict__ score,
                              const float* __restrict__ bc0, const float* __restrict__ bc1,
                              const float* __restrict__ bc2, const float* __restrict__ bc3) {
    int i = blockIdx.x * blockDim.x + threadIdx.x;
    if (i < NN) {
        float d = deg[i];
        deg[i] = 1.0f / fmaxf(d, 1.0f);   // in-place: deg -> inv_deg
    }
    if (i < GG) {
        float c = gcnt[i];
        gcnt[i] = 1.0f / fmaxf(c, 1.0f);  // in-place: gcnt -> inv_gcnt
        // seg_mean(feat@Wc + bc) = (sum feat@Wc)/cnt + bc for non-empty graphs, 0 for empty
        score[i] = (c > 0.0f) ? (bc0[0] + bc1[0] + bc2[0] + bc3[0]) : 0.0f;
    }
}

// ---------------- edge GEMM: m = relu([x[src], e] @ Wm + bm); atomic agg[dst] += m ----------------
// A is the gathered [E, FIN+16] matrix. fin is a multiple of 16, so each BK=16
// K-chunk is entirely in the x-part or entirely in the e-part -> aligned float4 loads.

template<int FIN, int F>
__global__ __launch_bounds__(256)
void edge_gemm(const float* __restrict__ feat, const float* __restrict__ ef,
               const int* __restrict__ src, const int* __restrict__ dst,
               const float* __restrict__ Wm, const float* __restrict__ bm,
               float* __restrict__ agg)
{
    constexpr int K = FIN + 16;  // EF = 16
    __shared__ __align__(16) float As[BK][BM];
    __shared__ __align__(16) float Bs[BK][BN];

    const int eb = blockIdx.x * BM;
    const int cb = blockIdx.y * BN;
    const int tid = threadIdx.x;

    const int rm = (tid & 15) * 4;   // micro-tile row base (edge)
    const int cn = (tid >> 4) * 4;   // micro-tile col base

    // A loader: lane = edge row (conflict-free LDS writes), 4 k's per thread
    const int le = tid & 63;         // edge row 0..63
    const int lk = (tid >> 6) * 4;   // k offset 0,4,8,12
    const int eg = eb + le;
    const int sg = src[eg];          // E divisible by BM -> always valid

    // B loader: row kk = tid/16, 4 cols per thread (coalesced global, conflict-free LDS)
    const int bkk = tid >> 4;
    const int bcc = (tid & 15) * 4;

    float acc[4][4] = {};

    for (int kb = 0; kb < K; kb += BK) {
        int k0 = kb + lk;
        float4 av;
        if (k0 < FIN) {
            av = *(const float4*)&feat[(size_t)sg * FIN + k0];
        } else {
            av = *(const float4*)&ef[(size_t)eg * 16 + (k0 - FIN)];
        }
        As[lk + 0][le] = av.x;
        As[lk + 1][le] = av.y;
        As[lk + 2][le] = av.z;
        As[lk + 3][le] = av.w;

        *(float4*)&Bs[bkk][bcc] = *(const float4*)&Wm[(size_t)(kb + bkk) * F + cb + bcc];

        __syncthreads();

        #pragma unroll
        for (int kk = 0; kk < BK; ++kk) {
            float4 a = *(const float4*)&As[kk][rm];
            float4 b = *(const float4*)&Bs[kk][cn];
            float ar[4] = {a.x, a.y, a.z, a.w};
            float br[4] = {b.x, b.y, b.z, b.w};
            #pragma unroll
            for (int i = 0; i < 4; ++i)
                #pragma unroll
                for (int j = 0; j < 4; ++j)
                    acc[i][j] = fmaf(ar[i], br[j], acc[i][j]);
        }
        __syncthreads();
    }

    float bmv[4];
    #pragma unroll
    for (int j = 0; j < 4; ++j) bmv[j] = bm[cb + cn + j];

    #pragma unroll
    for (int i = 0; i < 4; ++i) {
        int e = eb + rm + i;
        int d = dst[e];
        float* ap = &agg[(size_t)d * F + cb + cn];
        #pragma unroll
        for (int j = 0; j < 4; ++j) {
            float v = acc[i][j] + bmv[j];
            if (v > 0.0f) atomicAdd(&ap[j], v);  // relu: skip exact zeros
        }
    }
}

// ---------------- node GEMM: feat' = relu(agg*invdeg + feat@Ws + bs); score += seg_mean(feat'@Wc) ----------------

template<int FIN, int F>
__global__ __launch_bounds__(256)
void node_gemm(const float* __restrict__ feat, const float* __restrict__ agg,
               const float* __restrict__ Ws, const float* __restrict__ bs,
               const float* __restrict__ Wc, const float* __restrict__ invdeg,
               const float* __restrict__ invg, const int* __restrict__ gid,
               float* __restrict__ featN, float* __restrict__ score)
{
    __shared__ __align__(16) float As[BK][BM];
    __shared__ __align__(16) float Bs[BK][BN];
    __shared__ float rowsum[BM];

    const int nb = blockIdx.x * BM;
    const int cb = blockIdx.y * BN;
    const int tid = threadIdx.x;

    const int rm = (tid & 15) * 4;
    const int cn = (tid >> 4) * 4;

    const int ln = tid & 63;
    const int lk = (tid >> 6) * 4;
    const int ng = nb + ln;

    const int bkk = tid >> 4;
    const int bcc = (tid & 15) * 4;

    float acc[4][4] = {};

    for (int kb = 0; kb < FIN; kb += BK) {
        float4 av = make_float4(0.f, 0.f, 0.f, 0.f);
        if (ng < NN) av = *(const float4*)&feat[(size_t)ng * FIN + kb + lk];
        As[lk + 0][ln] = av.x;
        As[lk + 1][ln] = av.y;
        As[lk + 2][ln] = av.z;
        As[lk + 3][ln] = av.w;

        *(float4*)&Bs[bkk][bcc] = *(const float4*)&Ws[(size_t)(kb + bkk) * F + cb + bcc];

        __syncthreads();

        #pragma unroll
        for (int kk = 0; kk < BK; ++kk) {
            float4 a = *(const float4*)&As[kk][rm];
            float4 b = *(const float4*)&Bs[kk][cn];
            float ar[4] = {a.x, a.y, a.z, a.w};
            float br[4] = {b.x, b.y, b.z, b.w};
            #pragma unroll
            for (int i = 0; i < 4; ++i)
                #pragma unroll
                for (int j = 0; j < 4; ++j)
                    acc[i][j] = fmaf(ar[i], br[j], acc[i][j]);
        }
        __syncthreads();
    }

    if (tid < BM) rowsum[tid] = 0.0f;
    __syncthreads();

    float wcv[4], bsv[4];
    #pragma unroll
    for (int j = 0; j < 4; ++j) {
        wcv[j] = Wc[cb + cn + j];
        bsv[j] = bs[cb + cn + j];
    }

    #pragma unroll
    for (int i = 0; i < 4; ++i) {
        int n = nb + rm + i;
        if (n < NN) {
            float idg = invdeg[n];
            float4 ag = *(const float4*)&agg[(size_t)n * F + cb + cn];
            float agr[4] = {ag.x, ag.y, ag.z, ag.w};
            float4 out;
            float s = 0.0f;
            float v;
            v = fmaxf(acc[i][0] + agr[0] * idg + bsv[0], 0.0f); out.x = v; s += v * wcv[0];
            v = fmaxf(acc[i][1] + agr[1] * idg + bsv[1], 0.0f); out.y = v; s += v * wcv[1];
            v = fmaxf(acc[i][2] + agr[2] * idg + bsv[2], 0.0f); out.z = v; s += v * wcv[2];
            v = fmaxf(acc[i][3] + agr[3] * idg + bsv[3], 0.0f); out.w = v; s += v * wcv[3];
            *(float4*)&featN[(size_t)n * F + cb + cn] = out;
            atomicAdd(&rowsum[rm + i], s);
        }
    }
    __syncthreads();

    if (tid < BM) {
        int n = nb + tid;
        if (n < NN) {
            float s = rowsum[tid];
            if (s != 0.0f) {
                int g = gid[n];
                atomicAdd(&score[g], s * invg[g]);
            }
        }
    }
}

// ---------------- host ----------------

extern "C" void kernel_launch(void* const* d_in, const int* in_sizes, int n_in,
                              void* d_out, int out_size, void* d_ws, size_t ws_size,
                              hipStream_t stream) {
    const float* x   = (const float*)d_in[0];
    const float* ef  = (const float*)d_in[1];
    const int*   src = (const int*)d_in[2];
    const int*   dst = (const int*)d_in[3];
    const int*   gid = (const int*)d_in[4];
    const float *Wm[4], *bm[4], *Ws[4], *bs[4], *Wc[4], *bc[4];
    for (int i = 0; i < 4; ++i) {
        Wm[i] = (const float*)d_in[5 + 6 * i];
        bm[i] = (const float*)d_in[6 + 6 * i];
        Ws[i] = (const float*)d_in[7 + 6 * i];
        bs[i] = (const float*)d_in[8 + 6 * i];
        Wc[i] = (const float*)d_in[9 + 6 * i];
        bc[i] = (const float*)d_in[10 + 6 * i];
    }

    float* ws     = (float*)d_ws;
    float* agg    = ws;                          // N*256
    float* fA     = agg + (size_t)NN * 256;      // N*256
    float* fB     = fA + (size_t)NN * 256;       // N*256
    float* invdeg = fB + (size_t)NN * 256;       // N
    float* invg   = invdeg + NN;                 // G
    float* score  = (float*)d_out;

    hipMemsetAsync(invdeg, 0, NN * sizeof(float), stream);
    hipMemsetAsync(invg, 0, GG * sizeof(float), stream);
    count_deg<<<(EE + 255) / 256, 256, 0, stream>>>(dst, invdeg);
    count_g<<<(NN + 255) / 256, 256, 0, stream>>>(gid, invg);
    finalize_init<<<(NN + 255) / 256, 256, 0, stream>>>(invdeg, invg, score,
                                                        bc[0], bc[1], bc[2], bc[3]);

    // layer 0: fin=32, f=64, x -> fA
    hipMemsetAsync(agg, 0, (size_t)NN * 64 * sizeof(float), stream);
    edge_gemm<32, 64><<<dim3(EE / BM, 64 / BN), 256, 0, stream>>>(x, ef, src, dst, Wm[0], bm[0], agg);
    node_gemm<32, 64><<<dim3((NN + BM - 1) / BM, 64 / BN), 256, 0, stream>>>(x, agg, Ws[0], bs[0], Wc[0], invdeg, invg, gid, fA, score);

    // layer 1: fin=64, f=128, fA -> fB
    hipMemsetAsync(agg, 0, (size_t)NN * 128 * sizeof(float), stream);
    edge_gemm<64, 128><<<dim3(EE / BM, 128 / BN), 256, 0, stream>>>(fA, ef, src, dst, Wm[1], bm[1], agg);
    node_gemm<64, 128><<<dim3((NN + BM - 1) / BM, 128 / BN), 256, 0, stream>>>(fA, agg, Ws[1], bs[1], Wc[1], invdeg, invg, gid, fB, score);

    // layer 2: fin=128, f=128, fB -> fA
    hipMemsetAsync(agg, 0, (size_t)NN * 128 * sizeof(float), stream);
    edge_gemm<128, 128><<<dim3(EE / BM, 128 / BN), 256, 0, stream>>>(fB, ef, src, dst, Wm[2], bm[2], agg);
    node_gemm<128, 128><<<dim3((NN + BM - 1) / BM, 128 / BN), 256, 0, stream>>>(fB, agg, Ws[2], bs[2], Wc[2], invdeg, invg, gid, fA, score);

    // layer 3: fin=128, f=256, fA -> fB
    hipMemsetAsync(agg, 0, (size_t)NN * 256 * sizeof(float), stream);
    edge_gemm<128, 256><<<dim3(EE / BM, 256 / BN), 256, 0, stream>>>(fA, ef, src, dst, Wm[3], bm[3], agg);
    node_gemm<128, 256><<<dim3((NN + BM - 1) / BM, 256 / BN), 256, 0, stream>>>(fA, agg, Ws[3], bs[3], Wc[3], invdeg, invg, gid, fB, score);
}

// Round 2
// 3299.511 us; speedup vs baseline: 2.0323x; 2.0323x over previous
//
#include <hip/hip_runtime.h>

#define NN 50000
#define EE 800000
#define GG 512

#define BM 64
#define BN 64
#define BK 16
#define SUBT 4              // sub-tiles per edge block (256 edges/block)
#define RST 68              // red LDS row stride (64 + 4 pad, float4-aligned)

// ---------------- sort pipeline ----------------

__global__ void hist_kernel(const int* __restrict__ dst, int* __restrict__ hist) {
    int e = blockIdx.x * blockDim.x + threadIdx.x;
    if (e < EE) atomicAdd(&hist[dst[e]], 1);
}

__global__ void count_g(const int* __restrict__ gid, float* __restrict__ gcnt) {
    int n = blockIdx.x * blockDim.x + threadIdx.x;
    if (n < NN) atomicAdd(&gcnt[gid[n]], 1.0f);
}

// single-block exclusive scan of hist[0..NN-1] -> offs[0..NN]
__global__ __launch_bounds__(1024)
void scan_kernel(const int* __restrict__ hist, int* __restrict__ offs) {
    __shared__ int buf[1024];
    __shared__ int s_carry;
    const int tid = threadIdx.x;
    if (tid == 0) s_carry = 0;
    __syncthreads();
    for (int base = 0; base < NN + 1024; base += 1024) {
        int c = s_carry;
        int idx = base + tid;
        int v = (idx < NN) ? hist[idx] : 0;
        buf[tid] = v;
        __syncthreads();
        #pragma unroll
        for (int off = 1; off < 1024; off <<= 1) {
            int t = (tid >= off) ? buf[tid - off] : 0;
            __syncthreads();
            buf[tid] += t;
            __syncthreads();
        }
        int excl = buf[tid] - v;
        if (idx <= NN) offs[idx] = c + excl;
        __syncthreads();
        if (tid == 0) s_carry = c + buf[1023];
        __syncthreads();
    }
}

// scatter: perm position for each edge; emit sorted src / dst / orig-edge-id
__global__ void scatter_kernel(const int* __restrict__ src, const int* __restrict__ dst,
                               int* __restrict__ cursor,
                               int* __restrict__ srcS, int* __restrict__ dstS,
                               int* __restrict__ eS) {
    int e = blockIdx.x * blockDim.x + threadIdx.x;
    if (e < EE) {
        int d = dst[e];
        int p = atomicAdd(&cursor[d], 1);
        srcS[p] = src[e];
        dstS[p] = d;
        eS[p] = e;
    }
}

__global__ void finalize_init(const int* __restrict__ hist, float* __restrict__ invdeg,
                              float* __restrict__ gcnt, float* __restrict__ score,
                              const float* __restrict__ bc0, const float* __restrict__ bc1,
                              const float* __restrict__ bc2, const float* __restrict__ bc3) {
    int i = blockIdx.x * blockDim.x + threadIdx.x;
    if (i < NN) invdeg[i] = 1.0f / fmaxf((float)hist[i], 1.0f);
    if (i < GG) {
        float c = gcnt[i];
        gcnt[i] = 1.0f / fmaxf(c, 1.0f);
        score[i] = (c > 0.0f) ? (bc0[0] + bc1[0] + bc2[0] + bc3[0]) : 0.0f;
    }
}

// ---------------- edge GEMM over dst-sorted edges + segmented reduce ----------------
// Each block: 256 consecutive sorted edges (4 sub-tiles of 64) x 64 cols.
// Wave 0 does a wave-uniform segmented reduction over sorted-dst runs:
// interior runs -> plain coalesced stores; block-boundary runs -> atomics.

template<int FIN, int F>
__global__ __launch_bounds__(256)
void edge_gemm(const float* __restrict__ feat, const float* __restrict__ ef,
               const int* __restrict__ srcS, const int* __restrict__ dstS,
               const int* __restrict__ eS,
               const float* __restrict__ Wm, const float* __restrict__ bm,
               float* __restrict__ agg)
{
    constexpr int K = FIN + 16;
    __shared__ __align__(16) float As[BK][BM];
    __shared__ __align__(16) float Bs[BK][BN];
    __shared__ __align__(16) float red[BM * RST];
    __shared__ int sdst[BM * SUBT];

    const int base_e = blockIdx.x * (BM * SUBT);
    const int cb = blockIdx.y * BN;
    const int tid = threadIdx.x;

    const int rm = (tid & 15) * 4;
    const int cn = (tid >> 4) * 4;

    const int le = tid & 63;
    const int lk = (tid >> 6) * 4;

    const int bkk = tid >> 4;
    const int bcc = (tid & 15) * 4;

    // dst values for all 256 rows of this block
    sdst[tid] = dstS[base_e + tid];

    float bmv[4];
    #pragma unroll
    for (int j = 0; j < 4; ++j) bmv[j] = bm[cb + cn + j];

    // segmented-reduce state (wave 0, lane = column)
    int cur_d = -1, run_start = 0;
    float csum = 0.0f;

    for (int sub = 0; sub < SUBT; ++sub) {
        const int row0 = sub * BM;
        const int es = base_e + row0 + le;
        const int sg = srcS[es];
        const int eo = eS[es];

        float acc[4][4] = {};

        for (int kb = 0; kb < K; kb += BK) {
            int k0 = kb + lk;
            float4 av;
            if (k0 < FIN) {
                av = *(const float4*)&feat[(size_t)sg * FIN + k0];
            } else {
                av = *(const float4*)&ef[(size_t)eo * 16 + (k0 - FIN)];
            }
            As[lk + 0][le] = av.x;
            As[lk + 1][le] = av.y;
            As[lk + 2][le] = av.z;
            As[lk + 3][le] = av.w;

            *(float4*)&Bs[bkk][bcc] = *(const float4*)&Wm[(size_t)(kb + bkk) * F + cb + bcc];

            __syncthreads();

            #pragma unroll
            for (int kk = 0; kk < BK; ++kk) {
                float4 a = *(const float4*)&As[kk][rm];
                float4 b = *(const float4*)&Bs[kk][cn];
                float ar[4] = {a.x, a.y, a.z, a.w};
                float br[4] = {b.x, b.y, b.z, b.w};
                #pragma unroll
                for (int i = 0; i < 4; ++i)
                    #pragma unroll
                    for (int j = 0; j < 4; ++j)
                        acc[i][j] = fmaf(ar[i], br[j], acc[i][j]);
            }
            __syncthreads();
        }

        // relu(acc + bm) -> red LDS
        #pragma unroll
        for (int i = 0; i < 4; ++i) {
            float4 o;
            o.x = fmaxf(acc[i][0] + bmv[0], 0.0f);
            o.y = fmaxf(acc[i][1] + bmv[1], 0.0f);
            o.z = fmaxf(acc[i][2] + bmv[2], 0.0f);
            o.w = fmaxf(acc[i][3] + bmv[3], 0.0f);
            *(float4*)&red[(rm + i) * RST + cn] = o;
        }
        __syncthreads();

        // wave 0: segmented reduction down 64 rows (wave-uniform branches)
        if (tid < 64) {
            for (int r = 0; r < BM; ++r) {
                int g = row0 + r;
                int d = sdst[g];
                float v = red[r * RST + tid];
                if (g == 0) {
                    cur_d = d; csum = v; run_start = 0;
                } else if (d != cur_d) {
                    float* ap = &agg[(size_t)cur_d * F + cb + tid];
                    if (run_start > 0) *ap = csum;       // run complete inside block
                    else atomicAdd(ap, csum);            // touches block start
                    cur_d = d; csum = v; run_start = g;
                } else {
                    csum += v;
                }
            }
        }
        __syncthreads();
    }

    // final run touches block end -> atomic
    if (tid < 64) {
        atomicAdd(&agg[(size_t)cur_d * F + cb + tid], csum);
    }
}

// ---------------- node GEMM: feat' = relu(agg*invdeg + feat@Ws + bs); score += seg_mean(feat'@Wc) ----------------

template<int FIN, int F>
__global__ __launch_bounds__(256)
void node_gemm(const float* __restrict__ feat, const float* __restrict__ agg,
               const float* __restrict__ Ws, const float* __restrict__ bs,
               const float* __restrict__ Wc, const float* __restrict__ invdeg,
               const float* __restrict__ invg, const int* __restrict__ gid,
               float* __restrict__ featN, float* __restrict__ score)
{
    __shared__ __align__(16) float As[BK][BM];
    __shared__ __align__(16) float Bs[BK][BN];
    __shared__ float rowsum[BM];

    const int nb = blockIdx.x * BM;
    const int cb = blockIdx.y * BN;
    const int tid = threadIdx.x;

    const int rm = (tid & 15) * 4;
    const int cn = (tid >> 4) * 4;

    const int ln = tid & 63;
    const int lk = (tid >> 6) * 4;
    const int ng = nb + ln;

    const int bkk = tid >> 4;
    const int bcc = (tid & 15) * 4;

    float acc[4][4] = {};

    for (int kb = 0; kb < FIN; kb += BK) {
        float4 av = make_float4(0.f, 0.f, 0.f, 0.f);
        if (ng < NN) av = *(const float4*)&feat[(size_t)ng * FIN + kb + lk];
        As[lk + 0][ln] = av.x;
        As[lk + 1][ln] = av.y;
        As[lk + 2][ln] = av.z;
        As[lk + 3][ln] = av.w;

        *(float4*)&Bs[bkk][bcc] = *(const float4*)&Ws[(size_t)(kb + bkk) * F + cb + bcc];

        __syncthreads();

        #pragma unroll
        for (int kk = 0; kk < BK; ++kk) {
            float4 a = *(const float4*)&As[kk][rm];
            float4 b = *(const float4*)&Bs[kk][cn];
            float ar[4] = {a.x, a.y, a.z, a.w};
            float br[4] = {b.x, b.y, b.z, b.w};
            #pragma unroll
            for (int i = 0; i < 4; ++i)
                #pragma unroll
                for (int j = 0; j < 4; ++j)
                    acc[i][j] = fmaf(ar[i], br[j], acc[i][j]);
        }
        __syncthreads();
    }

    if (tid < BM) rowsum[tid] = 0.0f;
    __syncthreads();

    float wcv[4], bsv[4];
    #pragma unroll
    for (int j = 0; j < 4; ++j) {
        wcv[j] = Wc[cb + cn + j];
        bsv[j] = bs[cb + cn + j];
    }

    #pragma unroll
    for (int i = 0; i < 4; ++i) {
        int n = nb + rm + i;
        if (n < NN) {
            float idg = invdeg[n];
            float4 ag = *(const float4*)&agg[(size_t)n * F + cb + cn];
            float agr[4] = {ag.x, ag.y, ag.z, ag.w};
            float4 out;
            float s = 0.0f;
            float v;
            v = fmaxf(acc[i][0] + agr[0] * idg + bsv[0], 0.0f); out.x = v; s += v * wcv[0];
            v = fmaxf(acc[i][1] + agr[1] * idg + bsv[1], 0.0f); out.y = v; s += v * wcv[1];
            v = fmaxf(acc[i][2] + agr[2] * idg + bsv[2], 0.0f); out.z = v; s += v * wcv[2];
            v = fmaxf(acc[i][3] + agr[3] * idg + bsv[3], 0.0f); out.w = v; s += v * wcv[3];
            *(float4*)&featN[(size_t)n * F + cb + cn] = out;
            atomicAdd(&rowsum[rm + i], s);
        }
    }
    __syncthreads();

    if (tid < BM) {
        int n = nb + tid;
        if (n < NN) {
            float s = rowsum[tid];
            if (s != 0.0f) {
                int g = gid[n];
                atomicAdd(&score[g], s * invg[g]);
            }
        }
    }
}

// ---------------- host ----------------

extern "C" void kernel_launch(void* const* d_in, const int* in_sizes, int n_in,
                              void* d_out, int out_size, void* d_ws, size_t ws_size,
                              hipStream_t stream) {
    const float* x   = (const float*)d_in[0];
    const float* ef  = (const float*)d_in[1];
    const int*   src = (const int*)d_in[2];
    const int*   dst = (const int*)d_in[3];
    const int*   gid = (const int*)d_in[4];
    const float *Wm[4], *bm[4], *Ws[4], *bs[4], *Wc[4], *bc[4];
    for (int i = 0; i < 4; ++i) {
        Wm[i] = (const float*)d_in[5 + 6 * i];
        bm[i] = (const float*)d_in[6 + 6 * i];
        Ws[i] = (const float*)d_in[7 + 6 * i];
        bs[i] = (const float*)d_in[8 + 6 * i];
        Wc[i] = (const float*)d_in[9 + 6 * i];
        bc[i] = (const float*)d_in[10 + 6 * i];
    }

    char* w = (char*)d_ws;
    float* agg    = (float*)w;            w += (size_t)NN * 256 * 4;
    float* fA     = (float*)w;            w += (size_t)NN * 256 * 4;
    float* fB     = (float*)w;            w += (size_t)NN * 256 * 4;
    float* invdeg = (float*)w;            w += (size_t)NN * 4;
    float* invg   = (float*)w;            w += (size_t)GG * 4;
    int*   hist   = (int*)w;              w += (size_t)(NN + 1) * 4;
    int*   offs   = (int*)w;              w += (size_t)(NN + 1) * 4;
    int*   cursor = (int*)w;              w += (size_t)NN * 4;
    int*   srcS   = (int*)w;              w += (size_t)EE * 4;
    int*   dstS   = (int*)w;              w += (size_t)EE * 4;
    int*   eS     = (int*)w;              w += (size_t)EE * 4;
    float* score  = (float*)d_out;

    // ---- sort edges by dst (counting sort) ----
    hipMemsetAsync(hist, 0, (NN + 1) * sizeof(int), stream);
    hipMemsetAsync(invg, 0, GG * sizeof(float), stream);
    hist_kernel<<<(EE + 255) / 256, 256, 0, stream>>>(dst, hist);
    count_g<<<(NN + 255) / 256, 256, 0, stream>>>(gid, invg);
    scan_kernel<<<1, 1024, 0, stream>>>(hist, offs);
    hipMemcpyAsync(cursor, offs, NN * sizeof(int), hipMemcpyDeviceToDevice, stream);
    finalize_init<<<(NN + 255) / 256, 256, 0, stream>>>(hist, invdeg, invg, score,
                                                        bc[0], bc[1], bc[2], bc[3]);
    scatter_kernel<<<(EE + 255) / 256, 256, 0, stream>>>(src, dst, cursor, srcS, dstS, eS);

    const int EB = EE / (BM * SUBT);  // 3125 edge blocks

    // layer 0: fin=32, f=64, x -> fA
    hipMemsetAsync(agg, 0, (size_t)NN * 64 * sizeof(float), stream);
    edge_gemm<32, 64><<<dim3(EB, 1), 256, 0, stream>>>(x, ef, srcS, dstS, eS, Wm[0], bm[0], agg);
    node_gemm<32, 64><<<dim3((NN + BM - 1) / BM, 1), 256, 0, stream>>>(x, agg, Ws[0], bs[0], Wc[0], invdeg, invg, gid, fA, score);

    // layer 1: fin=64, f=128, fA -> fB
    hipMemsetAsync(agg, 0, (size_t)NN * 128 * sizeof(float), stream);
    edge_gemm<64, 128><<<dim3(EB, 2), 256, 0, stream>>>(fA, ef, srcS, dstS, eS, Wm[1], bm[1], agg);
    node_gemm<64, 128><<<dim3((NN + BM - 1) / BM, 2), 256, 0, stream>>>(fA, agg, Ws[1], bs[1], Wc[1], invdeg, invg, gid, fB, score);

    // layer 2: fin=128, f=128, fB -> fA
    hipMemsetAsync(agg, 0, (size_t)NN * 128 * sizeof(float), stream);
    edge_gemm<128, 128><<<dim3(EB, 2), 256, 0, stream>>>(fB, ef, srcS, dstS, eS, Wm[2], bm[2], agg);
    node_gemm<128, 128><<<dim3((NN + BM - 1) / BM, 2), 256, 0, stream>>>(fB, agg, Ws[2], bs[2], Wc[2], invdeg, invg, gid, fA, score);

    // layer 3: fin=128, f=256, fA -> fB
    hipMemsetAsync(agg, 0, (size_t)NN * 256 * sizeof(float), stream);
    edge_gemm<128, 256><<<dim3(EB, 4), 256, 0, stream>>>(fA, ef, srcS, dstS, eS, Wm[3], bm[3], agg);
    node_gemm<128, 256><<<dim3((NN + BM - 1) / BM, 4), 256, 0, stream>>>(fA, agg, Ws[3], bs[3], Wc[3], invdeg, invg, gid, fB, score);
}

// Round 3
// 1360.317 us; speedup vs baseline: 4.9294x; 2.4255x over previous
//
#include <hip/hip_runtime.h>

#define NN 50000
#define EE 800000
#define GG 512
#define NP 50048   // NN padded to multiple of 64

typedef short bf16x8 __attribute__((ext_vector_type(8)));
typedef float floatx4 __attribute__((ext_vector_type(4)));

__device__ inline unsigned short f2b(float f) {
    unsigned u = __float_as_uint(f);
    unsigned r = (u + 0x7fffu + ((u >> 16) & 1u)) >> 16;
    return (unsigned short)r;
}

// ---------------- conversion kernels ----------------

__global__ void conv_bf16x8(const float* __restrict__ s, unsigned short* __restrict__ d, long n8) {
    long i = (long)blockIdx.x * blockDim.x + threadIdx.x;
    if (i < n8) {
        float4 a = ((const float4*)s)[2 * i];
        float4 b = ((const float4*)s)[2 * i + 1];
        unsigned short o[8] = {f2b(a.x), f2b(a.y), f2b(a.z), f2b(a.w),
                               f2b(b.x), f2b(b.y), f2b(b.z), f2b(b.w)};
        ((uint4*)d)[i] = *(uint4*)o;
    }
}

// W [K x F] fp32 -> WT [F x Kp] bf16, zero-padded cols K..Kp-1
__global__ void tp_bf16(const float* __restrict__ W, unsigned short* __restrict__ WT,
                        int K, int F, int Kp) {
    int f = blockIdx.x;
    for (int k = threadIdx.x; k < Kp; k += blockDim.x)
        WT[(size_t)f * Kp + k] = (k < K) ? f2b(W[(size_t)k * F + f]) : (unsigned short)0;
}

// ---------------- sort pipeline ----------------

__global__ void hist_kernel(const int* __restrict__ dst, int* __restrict__ hist) {
    int e = blockIdx.x * blockDim.x + threadIdx.x;
    if (e < EE) atomicAdd(&hist[dst[e]], 1);
}

__global__ void count_g(const int* __restrict__ gid, float* __restrict__ gcnt) {
    int n = blockIdx.x * blockDim.x + threadIdx.x;
    if (n < NN) atomicAdd(&gcnt[gid[n]], 1.0f);
}

__global__ __launch_bounds__(1024)
void scan_kernel(const int* __restrict__ hist, int* __restrict__ offs) {
    __shared__ int buf[1024];
    __shared__ int s_carry;
    const int tid = threadIdx.x;
    if (tid == 0) s_carry = 0;
    __syncthreads();
    for (int base = 0; base < NN + 1024; base += 1024) {
        int c = s_carry;
        int idx = base + tid;
        int v = (idx < NN) ? hist[idx] : 0;
        buf[tid] = v;
        __syncthreads();
        #pragma unroll
        for (int off = 1; off < 1024; off <<= 1) {
            int t = (tid >= off) ? buf[tid - off] : 0;
            __syncthreads();
            buf[tid] += t;
            __syncthreads();
        }
        int excl = buf[tid] - v;
        if (idx <= NN) offs[idx] = c + excl;
        __syncthreads();
        if (tid == 0) s_carry = c + buf[1023];
        __syncthreads();
    }
}

__global__ void scatter_kernel(const int* __restrict__ src, const int* __restrict__ dst,
                               int* __restrict__ cursor,
                               int* __restrict__ srcS, int* __restrict__ dstS,
                               int* __restrict__ eS) {
    int e = blockIdx.x * blockDim.x + threadIdx.x;
    if (e < EE) {
        int d = dst[e];
        int p = atomicAdd(&cursor[d], 1);
        srcS[p] = src[e];
        dstS[p] = d;
        eS[p] = e;
    }
}

__global__ void finalize_init(const int* __restrict__ hist, float* __restrict__ invdeg,
                              float* __restrict__ gcnt, float* __restrict__ score,
                              const float* __restrict__ bc0, const float* __restrict__ bc1,
                              const float* __restrict__ bc2, const float* __restrict__ bc3) {
    int i = blockIdx.x * blockDim.x + threadIdx.x;
    if (i < NN) invdeg[i] = 1.0f / fmaxf((float)hist[i], 1.0f);
    if (i < GG) {
        float c = gcnt[i];
        gcnt[i] = 1.0f / fmaxf(c, 1.0f);
        score[i] = (c > 0.0f) ? (bc0[0] + bc1[0] + bc2[0] + bc3[0]) : 0.0f;
    }
}

// ---------------- edge MFMA GEMM + per-wave segmented reduce ----------------
// Block: 256 edges (4 waves x 64-edge subtile) x 64 cols (blockIdx.y).
// A-frags gathered direct from global bf16 feat/ef; B (WmT, [F][Kp] frag-order)
// staged 4KB/K-step in LDS shared by waves. Epilogue: each wave reduces its own
// 64 sorted-dst rows (interior runs -> stores, boundary runs -> atomics).

template<int FIN, int F>
__global__ __launch_bounds__(256)
void edge_mfma(const unsigned short* __restrict__ featB, const unsigned short* __restrict__ efB,
               const int* __restrict__ srcS, const int* __restrict__ dstS,
               const int* __restrict__ eS, const unsigned short* __restrict__ WmT,
               const float* __restrict__ bm, float* __restrict__ agg)
{
    constexpr int Kp = FIN + 32;
    __shared__ __align__(16) unsigned short Bs[2048];   // 4 nt x 4 q x 16 n x 8 bf16
    __shared__ float red[4][32 * 65];
    __shared__ int sdst[256];

    const int tid = threadIdx.x;
    const int w   = tid >> 6;
    const int l   = tid & 63;
    const int l16 = l & 15;
    const int q   = l >> 4;
    const int cb  = blockIdx.y * 64;
    const int blk_e = blockIdx.x * 256;
    const int be  = blk_e + w * 64;

    sdst[tid] = dstS[blk_e + tid];

    int srcr[4], er[4];
    #pragma unroll
    for (int mt = 0; mt < 4; ++mt) {
        srcr[mt] = srcS[be + mt * 16 + l16];
        er[mt]   = eS[be + mt * 16 + l16];
    }

    float bmv[4];
    #pragma unroll
    for (int nt = 0; nt < 4; ++nt) bmv[nt] = bm[cb + nt * 16 + l16];

    floatx4 acc[4][4];
    #pragma unroll
    for (int mt = 0; mt < 4; ++mt)
        #pragma unroll
        for (int nt = 0; nt < 4; ++nt)
            acc[mt][nt] = (floatx4){0.f, 0.f, 0.f, 0.f};

    // B staging mapping: thread t -> (nt=t>>6, n=(t>>2)&15, q=t&3)
    const int brow  = cb + (tid >> 2);
    const int bq8   = (tid & 3) * 8;
    const int bldsu = (tid >> 6) * 512 + (tid & 3) * 128 + ((tid >> 2) & 15) * 8;

    const bf16x8 ZV = {0, 0, 0, 0, 0, 0, 0, 0};

    // main K loop: pure feat part
    for (int kb = 0; kb < FIN; kb += 32) {
        __syncthreads();
        *(uint4*)&Bs[bldsu] = *(const uint4*)&WmT[(size_t)brow * Kp + kb + bq8];
        __syncthreads();
        bf16x8 bfr[4];
        #pragma unroll
        for (int nt = 0; nt < 4; ++nt)
            bfr[nt] = *(const bf16x8*)&Bs[nt * 512 + q * 128 + l16 * 8];
        #pragma unroll
        for (int mt = 0; mt < 4; ++mt) {
            bf16x8 a = *(const bf16x8*)&featB[(size_t)srcr[mt] * FIN + kb + q * 8];
            #pragma unroll
            for (int nt = 0; nt < 4; ++nt)
                acc[mt][nt] = __builtin_amdgcn_mfma_f32_16x16x32_bf16(a, bfr[nt], acc[mt][nt], 0, 0, 0);
        }
    }
    // tail step: k = FIN..FIN+31 = [ef(16) | zero-pad(16)]
    {
        __syncthreads();
        *(uint4*)&Bs[bldsu] = *(const uint4*)&WmT[(size_t)brow * Kp + FIN + bq8];
        __syncthreads();
        bf16x8 bfr[4];
        #pragma unroll
        for (int nt = 0; nt < 4; ++nt)
            bfr[nt] = *(const bf16x8*)&Bs[nt * 512 + q * 128 + l16 * 8];
        #pragma unroll
        for (int mt = 0; mt < 4; ++mt) {
            bf16x8 a = ZV;
            if (q < 2) a = *(const bf16x8*)&efB[(size_t)er[mt] * 16 + q * 8];
            #pragma unroll
            for (int nt = 0; nt < 4; ++nt)
                acc[mt][nt] = __builtin_amdgcn_mfma_f32_16x16x32_bf16(a, bfr[nt], acc[mt][nt], 0, 0, 0);
        }
    }

    // epilogue: relu(acc+bm) -> red, then per-wave segmented reduce over sorted dst
    int cur_d = -1;
    float csum = 0.f;
    bool from_start = false;

    #pragma unroll
    for (int h = 0; h < 2; ++h) {
        __syncthreads();
        #pragma unroll
        for (int mi = 0; mi < 2; ++mi) {
            int mt = h * 2 + mi;
            #pragma unroll
            for (int nt = 0; nt < 4; ++nt)
                #pragma unroll
                for (int r = 0; r < 4; ++r)
                    red[w][(mi * 16 + q * 4 + r) * 65 + nt * 16 + l16] =
                        fmaxf(acc[mt][nt][r] + bmv[nt], 0.f);
        }
        __syncthreads();
        for (int r = 0; r < 32; ++r) {
            int gr = h * 32 + r;
            int d = sdst[w * 64 + gr];
            float v = red[w][r * 65 + l];
            if (gr == 0) {
                cur_d = d; csum = v; from_start = true;
            } else if (d != cur_d) {
                float* ap = &agg[(size_t)cur_d * F + cb + l];
                if (from_start) atomicAdd(ap, csum);
                else *ap = csum;
                cur_d = d; csum = v; from_start = false;
            } else {
                csum += v;
            }
        }
    }
    atomicAdd(&agg[(size_t)cur_d * F + cb + l], csum);
}

// ---------------- node MFMA GEMM: feat' = relu(agg*invdeg + feat@Ws + bs); score ----------------

template<int FIN, int F>
__global__ __launch_bounds__(256)
void node_mfma(const unsigned short* __restrict__ featB, const float* __restrict__ agg,
               const unsigned short* __restrict__ WsT, const float* __restrict__ bs,
               const float* __restrict__ Wc, const float* __restrict__ invdeg,
               const float* __restrict__ invg, const int* __restrict__ gid,
               unsigned short* __restrict__ fout, float* __restrict__ score)
{
    __shared__ __align__(16) unsigned short Bs[2048];

    const int tid = threadIdx.x;
    const int w   = tid >> 6;
    const int l   = tid & 63;
    const int l16 = l & 15;
    const int q   = l >> 4;
    const int cb  = blockIdx.y * 64;
    const int nb  = blockIdx.x * 64;
    const int row = nb + w * 16 + l16;   // A row (padded buffer, always safe)

    floatx4 acc[4];
    #pragma unroll
    for (int nt = 0; nt < 4; ++nt) acc[nt] = (floatx4){0.f, 0.f, 0.f, 0.f};

    const int brow  = cb + (tid >> 2);
    const int bq8   = (tid & 3) * 8;
    const int bldsu = (tid >> 6) * 512 + (tid & 3) * 128 + ((tid >> 2) & 15) * 8;

    for (int kb = 0; kb < FIN; kb += 32) {
        __syncthreads();
        *(uint4*)&Bs[bldsu] = *(const uint4*)&WsT[(size_t)brow * FIN + kb + bq8];
        __syncthreads();
        bf16x8 a = *(const bf16x8*)&featB[(size_t)row * FIN + kb + q * 8];
        #pragma unroll
        for (int nt = 0; nt < 4; ++nt) {
            bf16x8 b = *(const bf16x8*)&Bs[nt * 512 + q * 128 + l16 * 8];
            acc[nt] = __builtin_amdgcn_mfma_f32_16x16x32_bf16(a, b, acc[nt], 0, 0, 0);
        }
    }

    float wcv[4], bsv[4];
    #pragma unroll
    for (int nt = 0; nt < 4; ++nt) {
        wcv[nt] = Wc[cb + nt * 16 + l16];
        bsv[nt] = bs[cb + nt * 16 + l16];
    }

    #pragma unroll
    for (int r = 0; r < 4; ++r) {
        int n = nb + w * 16 + q * 4 + r;
        bool valid = n < NN;
        float idg = valid ? invdeg[n] : 0.f;
        float s = 0.f;
        #pragma unroll
        for (int nt = 0; nt < 4; ++nt) {
            int col = cb + nt * 16 + l16;
            float av = valid ? agg[(size_t)n * F + col] : 0.f;
            float v = fmaxf(acc[nt][r] + av * idg + bsv[nt], 0.f);
            if (valid) fout[(size_t)n * F + col] = f2b(v);
            s += v * wcv[nt];
        }
        s += __shfl_xor(s, 1);
        s += __shfl_xor(s, 2);
        s += __shfl_xor(s, 4);
        s += __shfl_xor(s, 8);
        if (valid && l16 == 0) {
            int g = gid[n];
            atomicAdd(&score[g], s * invg[g]);
        }
    }
}

// ---------------- host ----------------

extern "C" void kernel_launch(void* const* d_in, const int* in_sizes, int n_in,
                              void* d_out, int out_size, void* d_ws, size_t ws_size,
                              hipStream_t stream) {
    const float* x   = (const float*)d_in[0];
    const float* ef  = (const float*)d_in[1];
    const int*   src = (const int*)d_in[2];
    const int*   dst = (const int*)d_in[3];
    const int*   gid = (const int*)d_in[4];
    const float *Wm[4], *bm[4], *Ws[4], *bs[4], *Wc[4], *bc[4];
    for (int i = 0; i < 4; ++i) {
        Wm[i] = (const float*)d_in[5 + 6 * i];
        bm[i] = (const float*)d_in[6 + 6 * i];
        Ws[i] = (const float*)d_in[7 + 6 * i];
        bs[i] = (const float*)d_in[8 + 6 * i];
        Wc[i] = (const float*)d_in[9 + 6 * i];
        bc[i] = (const float*)d_in[10 + 6 * i];
    }

    char* w = (char*)d_ws;
    float* agg = (float*)w;                 w += (size_t)NN * 256 * 4;
    unsigned short* xb  = (unsigned short*)w; w += (size_t)NP * 32 * 2;
    unsigned short* f1  = (unsigned short*)w; w += (size_t)NP * 64 * 2;
    unsigned short* f2  = (unsigned short*)w; w += (size_t)NP * 128 * 2;
    unsigned short* f3  = (unsigned short*)w; w += (size_t)NP * 128 * 2;
    unsigned short* f4  = (unsigned short*)w; w += (size_t)NP * 256 * 2;
    unsigned short* efB = (unsigned short*)w; w += (size_t)EE * 16 * 2;
    unsigned short* WmT0 = (unsigned short*)w; w += (size_t)64 * 64 * 2;
    unsigned short* WmT1 = (unsigned short*)w; w += (size_t)128 * 96 * 2;
    unsigned short* WmT2 = (unsigned short*)w; w += (size_t)128 * 160 * 2;
    unsigned short* WmT3 = (unsigned short*)w; w += (size_t)256 * 160 * 2;
    unsigned short* WsT0 = (unsigned short*)w; w += (size_t)64 * 32 * 2;
    unsigned short* WsT1 = (unsigned short*)w; w += (size_t)128 * 64 * 2;
    unsigned short* WsT2 = (unsigned short*)w; w += (size_t)128 * 128 * 2;
    unsigned short* WsT3 = (unsigned short*)w; w += (size_t)256 * 128 * 2;
    float* invdeg = (float*)w;              w += (size_t)NN * 4;
    float* invg   = (float*)w;              w += (size_t)GG * 4;
    int* srcS   = (int*)w;                  w += (size_t)EE * 4;
    int* dstS   = (int*)w;                  w += (size_t)EE * 4;
    int* eS     = (int*)w;                  w += (size_t)EE * 4;
    int* hist   = (int*)w;                  w += (size_t)(NN + 1) * 4;
    int* offs   = (int*)w;                  w += (size_t)(NN + 1) * 4;
    int* cursor = (int*)w;                  w += (size_t)NN * 4;
    float* score = (float*)d_out;

    // ---- conversions ----
    conv_bf16x8<<<((size_t)NN * 32 / 8 + 255) / 256, 256, 0, stream>>>(x, xb, (long)NN * 32 / 8);
    conv_bf16x8<<<((size_t)EE * 16 / 8 + 255) / 256, 256, 0, stream>>>(ef, efB, (long)EE * 16 / 8);
    tp_bf16<<<64,  256, 0, stream>>>(Wm[0], WmT0, 48, 64, 64);
    tp_bf16<<<128, 256, 0, stream>>>(Wm[1], WmT1, 80, 128, 96);
    tp_bf16<<<128, 256, 0, stream>>>(Wm[2], WmT2, 144, 128, 160);
    tp_bf16<<<256, 256, 0, stream>>>(Wm[3], WmT3, 144, 256, 160);
    tp_bf16<<<64,  256, 0, stream>>>(Ws[0], WsT0, 32, 64, 32);
    tp_bf16<<<128, 256, 0, stream>>>(Ws[1], WsT1, 64, 128, 64);
    tp_bf16<<<128, 256, 0, stream>>>(Ws[2], WsT2, 128, 128, 128);
    tp_bf16<<<256, 256, 0, stream>>>(Ws[3], WsT3, 128, 256, 128);

    // ---- sort edges by dst ----
    hipMemsetAsync(hist, 0, (NN + 1) * sizeof(int), stream);
    hipMemsetAsync(invg, 0, GG * sizeof(float), stream);
    hist_kernel<<<(EE + 255) / 256, 256, 0, stream>>>(dst, hist);
    count_g<<<(NN + 255) / 256, 256, 0, stream>>>(gid, invg);
    scan_kernel<<<1, 1024, 0, stream>>>(hist, offs);
    hipMemcpyAsync(cursor, offs, NN * sizeof(int), hipMemcpyDeviceToDevice, stream);
    finalize_init<<<(NN + 255) / 256, 256, 0, stream>>>(hist, invdeg, invg, score,
                                                        bc[0], bc[1], bc[2], bc[3]);
    scatter_kernel<<<(EE + 255) / 256, 256, 0, stream>>>(src, dst, cursor, srcS, dstS, eS);

    const int EB = EE / 256;           // 3125
    const int NB = (NN + 63) / 64;     // 782

    // layer 0: fin=32, f=64
    hipMemsetAsync(agg, 0, (size_t)NN * 64 * 4, stream);
    edge_mfma<32, 64><<<dim3(EB, 1), 256, 0, stream>>>(xb, efB, srcS, dstS, eS, WmT0, bm[0], agg);
    node_mfma<32, 64><<<dim3(NB, 1), 256, 0, stream>>>(xb, agg, WsT0, bs[0], Wc[0], invdeg, invg, gid, f1, score);

    // layer 1: fin=64, f=128
    hipMemsetAsync(agg, 0, (size_t)NN * 128 * 4, stream);
    edge_mfma<64, 128><<<dim3(EB, 2), 256, 0, stream>>>(f1, efB, srcS, dstS, eS, WmT1, bm[1], agg);
    node_mfma<64, 128><<<dim3(NB, 2), 256, 0, stream>>>(f1, agg, WsT1, bs[1], Wc[1], invdeg, invg, gid, f2, score);

    // layer 2: fin=128, f=128
    hipMemsetAsync(agg, 0, (size_t)NN * 128 * 4, stream);
    edge_mfma<128, 128><<<dim3(EB, 2), 256, 0, stream>>>(f2, efB, srcS, dstS, eS, WmT2, bm[2], agg);
    node_mfma<128, 128><<<dim3(NB, 2), 256, 0, stream>>>(f2, agg, WsT2, bs[2], Wc[2], invdeg, invg, gid, f3, score);

    // layer 3: fin=128, f=256
    hipMemsetAsync(agg, 0, (size_t)NN * 256 * 4, stream);
    edge_mfma<128, 256><<<dim3(EB, 4), 256, 0, stream>>>(f3, efB, srcS, dstS, eS, WmT3, bm[3], agg);
    node_mfma<128, 256><<<dim3(NB, 4), 256, 0, stream>>>(f3, agg, WsT3, bs[3], Wc[3], invdeg, invg, gid, f4, score);
}